// Round 19
// baseline (148.521 us; speedup 1.0000x reference)
//
#include <hip/hip_runtime.h>
#include <hip/hip_bf16.h>
#include <stdint.h>

// ---------------------------------------------------------------------------
// MultiScaleAttention: x[4,128,4096] -> 3x conv1x1+PReLU -> attention -> out
//   conv (fused transpose): Q [n][s][64] bf16 (*log2e), K/V in MFMA-fragment-
//   ready GLOBAL layouts (1KB contiguous per wave-fragment -> linear LDS
//   staging, zero bank conflicts). Split-bf16 MFMA for fp32-level accuracy.
//   attn: q=64/wave (q=256/block), KVBLK=32, 3-buffer LDS, T4 counted-vmcnt;
//   4 kv-splits (grid 256 = 1 block/CU). SPLIT-K FINISH: last block of each
//   (batch,qt) group (device-scope atomic counter + threadfence) combines the
//   4 OP/DEN partials in fixed order and writes the final output -- no
//   separate combine kernel. Counters reset per launch via hipMemsetAsync.
// KF layout: [n][t(32k)][d0(4)][slot(64)]*16B, slot=hi*32+l31 ->
//            K[t*32+l31][d0*16+hi*8 ..+8]
// VF layout: [n][t(32k)][dvb*2+kc(8)][slot(64)]*16B, slot=hi*32+l31 ->
//            V^T[dvb*32+l31][t*32+kc*16+hi*8 ..+8]
// ---------------------------------------------------------------------------

typedef float   f32x16 __attribute__((ext_vector_type(16)));
typedef __bf16  bf16x8 __attribute__((ext_vector_type(8)));
typedef __bf16  bf16x2 __attribute__((ext_vector_type(2)));
typedef unsigned int u32x4 __attribute__((ext_vector_type(4)));
typedef unsigned int u32x2 __attribute__((ext_vector_type(2)));

#define L2E 1.4426950408889634f

// workspace layout (bytes); ws_size ~268MB
#define Q_OFF   (0u)                          // [4][4096][64] bf16 = 2MB
#define KF_OFF  (2u << 20)                    // frag-K, 512KB/batch = 2MB
#define VF_OFF  (4u << 20)                    // frag-V, 1MB/batch = 4MB
#define DEN_OFF (8u << 20)                    // [4][16][4][256] f32 = 256KB
#define CNT_OFF ((8u << 20) + (256u << 10))   // 64 u32 group counters
#define WH_OFF  ((8u << 20) + (1u << 19))     // W hi bf16 [256][128] = 64KB
#define WL_OFF  (WH_OFF + (1u << 16))
#define OP_OFF  (9u << 20)                    // num bf16 [4][16][4][128][256] = 16.8MB

__device__ inline unsigned short f2bf(float f) {   // hw v_cvt (RNE)
  __bf16 h = (__bf16)f;
  return __builtin_bit_cast(unsigned short, h);
}
__device__ inline float bf2f(unsigned short h) {
  unsigned u = ((unsigned)h) << 16;
  return __builtin_bit_cast(float, u);
}
__device__ inline unsigned pack2(float a, float b) {   // v_cvt_pk_bf16_f32
  bf16x2 t = { (__bf16)a, (__bf16)b };
  return __builtin_bit_cast(unsigned, t);
}

__device__ inline void gld_lds16(const void* g, void* l) {
  __builtin_amdgcn_global_load_lds(
      (const __attribute__((address_space(1))) unsigned*)g,
      (__attribute__((address_space(3))) unsigned*)l, 16, 0, 0);
}

// --------------------------- kernel 0: cast weights ------------------------
__global__ void wcast_kernel(const float* __restrict__ w1, const float* __restrict__ w2,
                             const float* __restrict__ wa, char* __restrict__ ws) {
  int idx = blockIdx.x * 256 + threadIdx.x;   // 32 blocks
  unsigned short* WH = (unsigned short*)(ws + WH_OFF);
  unsigned short* WL = (unsigned short*)(ws + WL_OFF);
#pragma unroll
  for (int r = 0; r < 4; ++r) {
    int i = r * 8192 + idx;                   // 0..32767
    int oc = i >> 7, c = i & 127;
    float v = oc < 64 ? w1[oc * 128 + c]
            : (oc < 128 ? w2[(oc - 64) * 128 + c] : wa[(oc - 128) * 128 + c]);
    __bf16 h = (__bf16)v;
    WH[i] = __builtin_bit_cast(unsigned short, h);
    WL[i] = f2bf(v - (float)h);
  }
}

// ------- kernel 1: conv1x1 + bias + PReLU -> Q, KF, VF (fused transpose) ----
// 512 blocks = 4n * 128 s-tiles(32). Waves: 0->Q(*L2E), 1->K, 2,3->V.
__global__ __launch_bounds__(256) void conv_kernel(
    const float* __restrict__ x, char* __restrict__ ws,
    const float* __restrict__ b1, const float* __restrict__ a1,
    const float* __restrict__ b2, const float* __restrict__ a2,
    const float* __restrict__ ba, const float* __restrict__ aa) {
  int bid = blockIdx.x;
  int n = bid >> 7, st = bid & 127;           // st == kv tile index t
  int sb = st * 32;
  int tid = threadIdx.x;
  int wid = tid >> 6, lane = tid & 63, l31 = lane & 31, hi = lane >> 5;

  __shared__ float xl[128][36];         // x-tile transpose; later reused as vl
  __shared__ float tl[2][64][33];       // Q/K f32 transpose buffers
  float* vl = (float*)xl;               // [128][33] V f32, reuse after MFMA

  const float* xb = x + (size_t)n * 128 * 4096;
#pragma unroll
  for (int it = 0; it < 4; ++it) {      // load 128x32 f32 tile
    int flat4 = tid + 256 * it;
    int c = flat4 >> 3, s4 = flat4 & 7;
    float4 v = *(const float4*)(xb + (size_t)c * 4096 + sb + s4 * 4);
    *(float4*)&xl[c][s4 * 4] = v;
  }
  __syncthreads();

  const char* WH = ws + WH_OFF;
  const char* WL = ws + WL_OFF;
  int oc0 = wid * 64;

  f32x16 acc[2];
  acc[0] = 0.f; acc[1] = 0.f;
#pragma unroll
  for (int c0 = 0; c0 < 8; ++c0) {
    __bf16 eh[8], el[8];
#pragma unroll
    for (int j = 0; j < 8; ++j) {
      float v = xl[c0 * 16 + hi * 8 + j][l31];
      __bf16 h = (__bf16)v;
      eh[j] = h;
      el[j] = (__bf16)(v - (float)h);
    }
    bf16x8 xh = {eh[0], eh[1], eh[2], eh[3], eh[4], eh[5], eh[6], eh[7]};
    bf16x8 xlo = {el[0], el[1], el[2], el[3], el[4], el[5], el[6], el[7]};
#pragma unroll
    for (int mb = 0; mb < 2; ++mb) {
      size_t wo = (size_t)(oc0 + mb * 32 + l31) * 256 + c0 * 32 + hi * 16;
      bf16x8 wh = *(const bf16x8*)(WH + wo);
      bf16x8 wl = *(const bf16x8*)(WL + wo);
      acc[mb] = __builtin_amdgcn_mfma_f32_32x32x16_bf16(wh, xh, acc[mb], 0, 0, 0);
      acc[mb] = __builtin_amdgcn_mfma_f32_32x32x16_bf16(wh, xlo, acc[mb], 0, 0, 0);
      acc[mb] = __builtin_amdgcn_mfma_f32_32x32x16_bf16(wl, xh, acc[mb], 0, 0, 0);
    }
  }
  __syncthreads();                      // all waves done reading xl

  if (wid < 2) {
    const float* bb = wid ? b2 : b1;
    float slope = wid ? a2[0] : a1[0];
    float scl = wid ? 1.0f : L2E;       // fold softmax log2e into Q
#pragma unroll
    for (int mb = 0; mb < 2; ++mb)
#pragma unroll
      for (int reg = 0; reg < 16; ++reg) {
        int row = mb * 32 + (reg & 3) + 8 * (reg >> 2) + 4 * hi;
        float y = acc[mb][reg] + bb[row];
        y = fmaxf(y, 0.f) + slope * fminf(y, 0.f);
        tl[wid][row][l31] = y * scl;
      }
  } else {
    float slope = aa[0];
#pragma unroll
    for (int mb = 0; mb < 2; ++mb)
#pragma unroll
      for (int reg = 0; reg < 16; ++reg) {
        int dv = (wid - 2) * 64 + mb * 32 + (reg & 3) + 8 * (reg >> 2) + 4 * hi;
        float y = acc[mb][reg] + ba[dv];
        y = fmaxf(y, 0.f) + slope * fminf(y, 0.f);
        vl[dv * 33 + l31] = y;
      }
  }
  __syncthreads();

  if (wid == 0) {                       // Q natural [s][64] bf16
    char* Qg = ws + Q_OFF + (size_t)n * (4096 * 128);
#pragma unroll
    for (int it = 0; it < 4; ++it) {
      int sl = (lane >> 3) + it * 8;
      u32x4 pv;
#pragma unroll
      for (int p = 0; p < 4; ++p)
        pv[p] = pack2(tl[0][(lane & 7) * 8 + 2 * p][sl],
                      tl[0][(lane & 7) * 8 + 2 * p + 1][sl]);
      *(u32x4*)(Qg + (size_t)(sb + sl) * 128 + (lane & 7) * 16) = pv;
    }
  } else if (wid == 1) {                // K fragment layout
    char* KFb = ws + KF_OFF + (size_t)n * (512 << 10);
    int d0 = (lane & 7) >> 1, hs = lane & 1;
#pragma unroll
    for (int it = 0; it < 4; ++it) {
      int sl = (lane >> 3) + it * 8;
      u32x4 pv;
#pragma unroll
      for (int p = 0; p < 4; ++p)
        pv[p] = pack2(tl[1][(lane & 7) * 8 + 2 * p][sl],
                      tl[1][(lane & 7) * 8 + 2 * p + 1][sl]);
      *(u32x4*)(KFb + ((size_t)(st * 4 + d0) * 64 + hs * 32 + sl) * 16) = pv;
    }
  }
  // all 256 threads: V fragment stores (512 units of 16B)
  {
    char* VFb = ws + VF_OFF + (size_t)n * (1u << 20);
#pragma unroll
    for (int r = 0; r < 2; ++r) {
      int u = tid + r * 256;
      int dv = u >> 2, sc = u & 3;
      u32x4 pv;
#pragma unroll
      for (int p = 0; p < 4; ++p)
        pv[p] = pack2(vl[dv * 33 + sc * 8 + 2 * p], vl[dv * 33 + sc * 8 + 2 * p + 1]);
      int unit = st * 8 + (dv >> 5) * 2 + (sc >> 1);
      *(u32x4*)(VFb + ((size_t)unit * 64 + (sc & 1) * 32 + (dv & 31)) * 16) = pv;
    }
  }
}

// --------------------------- kernel 2: flash attention + split-K finish -----
// 256 blocks: bid = ((batch*16+qt)<<2)|split -> 1 block/CU exactly.
// Block = 4 waves * 64 q = 256 q; kv = split*1024..+1024 (32 tiles of 32).
// 3-buffer LDS (36KB), stage distance 2; region:
//   {s_waitcnt vmcnt(3); s_barrier; stage(t+2); QK(t)+SM(t)+PV(t)}
// Last split-block of each (batch,qt) group combines partials -> out.
__global__ __launch_bounds__(256, 2) void attn_kernel(char* __restrict__ ws,
                                                      float* __restrict__ out) {
  int bid = blockIdx.x;
  int split = bid & 3;
  int qt = (bid >> 2) & 15;
  int batch = bid >> 6;
  int tid = threadIdx.x;
  int wid = tid >> 6, lane = tid & 63, l31 = lane & 31, hi = lane >> 5;

  const char* Qb  = ws + Q_OFF  + (size_t)batch * (4096 * 128);
  const char* Kt0 = ws + KF_OFF + (size_t)batch * (512 << 10) +
                    (size_t)(split * 32) * 4096;
  const char* Vt0 = ws + VF_OFF + (size_t)batch * (1u << 20) +
                    (size_t)(split * 32) * 8192;

  __shared__ char sbuf[3][12288];       // [0,4K)=K tile, [4K,12K)=V tile
  __shared__ int lastFlag;

  int q0 = qt * 256 + wid * 64;
  int lo16 = lane * 16;

  bf16x8 qf0[4], qf1[4];                // Q frags for the wave's 2 q-sets
#pragma unroll
  for (int d0 = 0; d0 < 4; ++d0) {
    qf0[d0] = *(const bf16x8*)(Qb + (size_t)(q0 + l31) * 128 + d0 * 32 + hi * 16);
    qf1[d0] = *(const bf16x8*)(Qb + (size_t)(q0 + 32 + l31) * 128 + d0 * 32 + hi * 16);
  }

  f32x16 oacc[2][4];
#pragma unroll
  for (int qs = 0; qs < 2; ++qs)
#pragma unroll
    for (int i = 0; i < 4; ++i) oacc[qs][i] = 0.f;
  float denA0 = 0.f, denA1 = 0.f, denB0 = 0.f, denB1 = 0.f;

  // each wave stages 3 of the 12 1KB chunks (K: c<4, V: c>=4)
  auto stage = [&](int b, int t) {
#pragma unroll
    for (int i = 0; i < 3; ++i) {
      int c = wid * 3 + i;
      const char* src = (c < 4) ? Kt0 + (size_t)t * 4096 + c * 1024 + lo16
                                : Vt0 + (size_t)t * 8192 + (c - 4) * 1024 + lo16;
      gld_lds16(src, &sbuf[b][c * 1024]);
    }
  };

  stage(0, 0);                          // 3 outstanding (this wave)
  stage(1, 1);                          // 6 outstanding

  for (int t = 0; t < 32; ++t) {
    // wait ONLY for tile t's 3 loads (issued 2 regions ago); t+1's in flight
    if (t < 31) asm volatile("s_waitcnt vmcnt(3)" ::: "memory");
    else        asm volatile("s_waitcnt vmcnt(0)" ::: "memory");
    __builtin_amdgcn_s_barrier();       // raw: no drain; all waves' chunks in

    if (t + 2 < 32) stage((t + 2) % 3, t + 2);   // overlaps this region

    const char* kb = sbuf[t % 3];
    const char* vb = kb + 4096;

    // QK both q-sets: S^T[k][q], k = (reg&3)+8*(reg>>2)+4*hi, q = l31
    f32x16 s0, s1;
    s0 = 0.f; s1 = 0.f;
#pragma unroll
    for (int d0 = 0; d0 < 4; ++d0) {
      bf16x8 kf = *(const bf16x8*)(kb + d0 * 1024 + lo16);
      s0 = __builtin_amdgcn_mfma_f32_32x32x16_bf16(kf, qf0[d0], s0, 0, 0, 0);
      s1 = __builtin_amdgcn_mfma_f32_32x32x16_bf16(kf, qf1[d0], s1, 0, 0, 0);
    }

    // softmax: p = exp2(s) (Q pre-scaled by log2e), unnormalized
    unsigned pk0[8], pk1[8];
#pragma unroll
    for (int m = 0; m < 8; ++m) {
      float a0 = __builtin_amdgcn_exp2f(s0[2 * m]);
      float a1 = __builtin_amdgcn_exp2f(s0[2 * m + 1]);
      if (m & 1) denA1 += a0 + a1; else denA0 += a0 + a1;
      pk0[m] = pack2(a0, a1);
      float b0 = __builtin_amdgcn_exp2f(s1[2 * m]);
      float b1 = __builtin_amdgcn_exp2f(s1[2 * m + 1]);
      if (m & 1) denB1 += b0 + b1; else denB0 += b0 + b1;
      pk1[m] = pack2(b0, b1);
    }

    // PV: O^T[dv][q] += V^T · P^T ; each vf read feeds both q-sets
#pragma unroll
    for (int kc = 0; kc < 2; ++kc) {
      const int bs = kc * 4;
      u32x2 r0 = __builtin_amdgcn_permlane32_swap(pk0[bs + 0], pk0[bs + 2],
                                                  false, false);
      u32x2 r1 = __builtin_amdgcn_permlane32_swap(pk0[bs + 1], pk0[bs + 3],
                                                  false, false);
      u32x4 pu0 = {r0.x, r1.x, r0.y, r1.y};
      bf16x8 pf0 = __builtin_bit_cast(bf16x8, pu0);
      u32x2 r2 = __builtin_amdgcn_permlane32_swap(pk1[bs + 0], pk1[bs + 2],
                                                  false, false);
      u32x2 r3 = __builtin_amdgcn_permlane32_swap(pk1[bs + 1], pk1[bs + 3],
                                                  false, false);
      u32x4 pu1 = {r2.x, r3.x, r2.y, r3.y};
      bf16x8 pf1 = __builtin_bit_cast(bf16x8, pu1);
#pragma unroll
      for (int dvb = 0; dvb < 4; ++dvb) {
        bf16x8 vf = *(const bf16x8*)(vb + (dvb * 2 + kc) * 1024 + lo16);
        oacc[0][dvb] = __builtin_amdgcn_mfma_f32_32x32x16_bf16(vf, pf0,
                                                               oacc[0][dvb], 0, 0, 0);
        oacc[1][dvb] = __builtin_amdgcn_mfma_f32_32x32x16_bf16(vf, pf1,
                                                               oacc[1][dvb], 0, 0, 0);
      }
    }
    // no trailing barrier: next region's top barrier provides WAR safety
  }

  // write numerator partials (bf16, cacheable) + denominator (f32)
  int grp = batch * 16 + qt;
  unsigned short* OPu = (unsigned short*)(ws + OP_OFF) +
                        (size_t)(grp * 4 + split) * 32768;
#pragma unroll
  for (int qs = 0; qs < 2; ++qs) {
    int qloc = wid * 64 + qs * 32 + l31;
#pragma unroll
    for (int dvb = 0; dvb < 4; ++dvb)
#pragma unroll
      for (int reg = 0; reg < 16; ++reg) {
        int dv = dvb * 32 + (reg & 3) + 8 * (reg >> 2) + 4 * hi;
        OPu[dv * 256 + qloc] = f2bf(oacc[qs][dvb][reg]);
      }
    float den = qs ? (denB0 + denB1) : (denA0 + denA1);
    float dtot = den + __shfl_xor(den, 32, 64);
    if (hi == 0) {
      float* DEN = (float*)(ws + DEN_OFF) + (size_t)(grp * 4 + split) * 256;
      DEN[qloc] = dtot;
    }
  }

  // ---- split-K finish: last arriving block of the group combines ----
  __threadfence();                      // release: OP/DEN visible device-wide
  if (tid == 0) {
    unsigned* cnt = (unsigned*)(ws + CNT_OFF);
    unsigned old = atomicAdd(&cnt[grp], 1u);
    lastFlag = (old == 3u) ? 1 : 0;
  }
  __syncthreads();
  if (lastFlag) {
    __threadfence();                    // acquire: see other splits' stores
    const unsigned short* OPg = (const unsigned short*)(ws + OP_OFF) +
                                (size_t)grp * 4 * 32768;
    const float* DENg = (const float*)(ws + DEN_OFF) + (size_t)grp * 4 * 256;
    int dv = tid >> 1;
    int qlb = (tid & 1) * 128;
    float* og = out + ((size_t)batch * 128 + dv) * 4096 + qt * 256 + qlb;
#pragma unroll
    for (int u = 0; u < 16; ++u) {
      int ql = qlb + u * 8;
      float num[8], den[8];
#pragma unroll
      for (int j = 0; j < 8; ++j) { num[j] = 0.f; den[j] = 0.f; }
#pragma unroll
      for (int sp = 0; sp < 4; ++sp) {  // fixed order -> deterministic
        bf16x8 v = *(const bf16x8*)(OPg + sp * 32768 + dv * 256 + ql);
        const float* dp = DENg + sp * 256 + ql;
        float4 d0 = *(const float4*)dp;
        float4 d1 = *(const float4*)(dp + 4);
#pragma unroll
        for (int j = 0; j < 8; ++j) num[j] += (float)v[j];
        den[0] += d0.x; den[1] += d0.y; den[2] += d0.z; den[3] += d0.w;
        den[4] += d1.x; den[5] += d1.y; den[6] += d1.z; den[7] += d1.w;
      }
      float4 o0 = {num[0] / den[0], num[1] / den[1], num[2] / den[2], num[3] / den[3]};
      float4 o1 = {num[4] / den[4], num[5] / den[5], num[6] / den[6], num[7] / den[7]};
      *(float4*)(og + u * 8) = o0;
      *(float4*)(og + u * 8 + 4) = o1;
    }
  }
}

// ---------------------------------------------------------------------------
extern "C" void kernel_launch(void* const* d_in, const int* in_sizes, int n_in,
                              void* d_out, int out_size, void* d_ws, size_t ws_size,
                              hipStream_t stream) {
  (void)in_sizes; (void)n_in; (void)out_size; (void)ws_size;
  const float* x  = (const float*)d_in[0];
  const float* w1 = (const float*)d_in[1];
  const float* b1 = (const float*)d_in[2];
  const float* a1 = (const float*)d_in[3];
  const float* w2 = (const float*)d_in[4];
  const float* b2 = (const float*)d_in[5];
  const float* a2 = (const float*)d_in[6];
  const float* wa = (const float*)d_in[7];
  const float* ba = (const float*)d_in[8];
  const float* aa = (const float*)d_in[9];
  char* ws = (char*)d_ws;
  float* out = (float*)d_out;

  hipMemsetAsync(ws + CNT_OFF, 0, 64 * sizeof(unsigned), stream);
  wcast_kernel<<<dim3(32), dim3(256), 0, stream>>>(w1, w2, wa, ws);
  conv_kernel<<<dim3(512), dim3(256), 0, stream>>>(x, ws, b1, a1, b2, a2, ba, aa);
  attn_kernel<<<dim3(256), dim3(256), 0, stream>>>(ws, out);
}

// Round 20
// 61.075 us; speedup vs baseline: 2.4318x; 2.4318x over previous
//
#include <hip/hip_runtime.h>
#include <hip/hip_bf16.h>
#include <stdint.h>

// ---------------------------------------------------------------------------
// MultiScaleAttention: x[4,128,4096] -> 3x conv1x1+PReLU -> attention -> out
//   conv (fused transpose): Q [n][s][64] bf16 (*log2e), K/V in MFMA-fragment-
//   ready GLOBAL layouts (1KB contiguous per wave-fragment). Split-bf16 MFMA.
//   attn: IN-BLOCK SPLIT-K. Grid 256 = 1 block/CU; block owns (batch, 64 q);
//   kv split across the 4 waves (1024 kv each, 32 tiles of 32). Each wave runs
//   a private barrier-FREE 3-buffer pipeline in its own 36KB LDS region,
//   self-paced with s_waitcnt vmcnt(12) (tile t+1 stays in flight). Partials
//   exchanged through LDS (2 barriers total); block writes final out directly.
//   No OP/DEN global traffic, no combine kernel, no device fences.
// KF layout: [n][t(32k)][d0(4)][slot(64)]*16B, slot=hi*32+l31 ->
//            K[t*32+l31][d0*16+hi*8 ..+8]
// VF layout: [n][t(32k)][dvb*2+kc(8)][slot(64)]*16B, slot=hi*32+l31 ->
//            V^T[dvb*32+l31][t*32+kc*16+hi*8 ..+8]
// ---------------------------------------------------------------------------

typedef float   f32x16 __attribute__((ext_vector_type(16)));
typedef __bf16  bf16x8 __attribute__((ext_vector_type(8)));
typedef __bf16  bf16x2 __attribute__((ext_vector_type(2)));
typedef unsigned int u32x4 __attribute__((ext_vector_type(4)));
typedef unsigned int u32x2 __attribute__((ext_vector_type(2)));

#define L2E 1.4426950408889634f

// workspace layout (bytes); ws_size ~268MB
#define Q_OFF   (0u)                          // [4][4096][64] bf16 = 2MB
#define KF_OFF  (2u << 20)                    // frag-K, 512KB/batch = 2MB
#define VF_OFF  (4u << 20)                    // frag-V, 1MB/batch = 4MB
#define WH_OFF  ((8u << 20) + (1u << 19))     // W hi bf16 [256][128] = 64KB
#define WL_OFF  (WH_OFF + (1u << 16))

__device__ inline unsigned short f2bf(float f) {   // hw v_cvt (RNE)
  __bf16 h = (__bf16)f;
  return __builtin_bit_cast(unsigned short, h);
}
__device__ inline float bf2f(unsigned short h) {
  unsigned u = ((unsigned)h) << 16;
  return __builtin_bit_cast(float, u);
}
__device__ inline unsigned pack2(float a, float b) {   // v_cvt_pk_bf16_f32
  bf16x2 t = { (__bf16)a, (__bf16)b };
  return __builtin_bit_cast(unsigned, t);
}

__device__ inline void gld_lds16(const void* g, void* l) {
  __builtin_amdgcn_global_load_lds(
      (const __attribute__((address_space(1))) unsigned*)g,
      (__attribute__((address_space(3))) unsigned*)l, 16, 0, 0);
}

// --------------------------- kernel 0: cast weights ------------------------
__global__ void wcast_kernel(const float* __restrict__ w1, const float* __restrict__ w2,
                             const float* __restrict__ wa, char* __restrict__ ws) {
  int idx = blockIdx.x * 256 + threadIdx.x;   // 32 blocks
  unsigned short* WH = (unsigned short*)(ws + WH_OFF);
  unsigned short* WL = (unsigned short*)(ws + WL_OFF);
#pragma unroll
  for (int r = 0; r < 4; ++r) {
    int i = r * 8192 + idx;                   // 0..32767
    int oc = i >> 7, c = i & 127;
    float v = oc < 64 ? w1[oc * 128 + c]
            : (oc < 128 ? w2[(oc - 64) * 128 + c] : wa[(oc - 128) * 128 + c]);
    __bf16 h = (__bf16)v;
    WH[i] = __builtin_bit_cast(unsigned short, h);
    WL[i] = f2bf(v - (float)h);
  }
}

// ------- kernel 1: conv1x1 + bias + PReLU -> Q, KF, VF (fused transpose) ----
// 512 blocks = 4n * 128 s-tiles(32). Waves: 0->Q(*L2E), 1->K, 2,3->V.
__global__ __launch_bounds__(256) void conv_kernel(
    const float* __restrict__ x, char* __restrict__ ws,
    const float* __restrict__ b1, const float* __restrict__ a1,
    const float* __restrict__ b2, const float* __restrict__ a2,
    const float* __restrict__ ba, const float* __restrict__ aa) {
  int bid = blockIdx.x;
  int n = bid >> 7, st = bid & 127;           // st == kv tile index t
  int sb = st * 32;
  int tid = threadIdx.x;
  int wid = tid >> 6, lane = tid & 63, l31 = lane & 31, hi = lane >> 5;

  __shared__ float xl[128][36];         // x-tile transpose; later reused as vl
  __shared__ float tl[2][64][33];       // Q/K f32 transpose buffers
  float* vl = (float*)xl;               // [128][33] V f32, reuse after MFMA

  const float* xb = x + (size_t)n * 128 * 4096;
#pragma unroll
  for (int it = 0; it < 4; ++it) {      // load 128x32 f32 tile
    int flat4 = tid + 256 * it;
    int c = flat4 >> 3, s4 = flat4 & 7;
    float4 v = *(const float4*)(xb + (size_t)c * 4096 + sb + s4 * 4);
    *(float4*)&xl[c][s4 * 4] = v;
  }
  __syncthreads();

  const char* WH = ws + WH_OFF;
  const char* WL = ws + WL_OFF;
  int oc0 = wid * 64;

  f32x16 acc[2];
  acc[0] = 0.f; acc[1] = 0.f;
#pragma unroll
  for (int c0 = 0; c0 < 8; ++c0) {
    __bf16 eh[8], el[8];
#pragma unroll
    for (int j = 0; j < 8; ++j) {
      float v = xl[c0 * 16 + hi * 8 + j][l31];
      __bf16 h = (__bf16)v;
      eh[j] = h;
      el[j] = (__bf16)(v - (float)h);
    }
    bf16x8 xh = {eh[0], eh[1], eh[2], eh[3], eh[4], eh[5], eh[6], eh[7]};
    bf16x8 xlo = {el[0], el[1], el[2], el[3], el[4], el[5], el[6], el[7]};
#pragma unroll
    for (int mb = 0; mb < 2; ++mb) {
      size_t wo = (size_t)(oc0 + mb * 32 + l31) * 256 + c0 * 32 + hi * 16;
      bf16x8 wh = *(const bf16x8*)(WH + wo);
      bf16x8 wl = *(const bf16x8*)(WL + wo);
      acc[mb] = __builtin_amdgcn_mfma_f32_32x32x16_bf16(wh, xh, acc[mb], 0, 0, 0);
      acc[mb] = __builtin_amdgcn_mfma_f32_32x32x16_bf16(wh, xlo, acc[mb], 0, 0, 0);
      acc[mb] = __builtin_amdgcn_mfma_f32_32x32x16_bf16(wl, xh, acc[mb], 0, 0, 0);
    }
  }
  __syncthreads();                      // all waves done reading xl

  if (wid < 2) {
    const float* bb = wid ? b2 : b1;
    float slope = wid ? a2[0] : a1[0];
    float scl = wid ? 1.0f : L2E;       // fold softmax log2e into Q
#pragma unroll
    for (int mb = 0; mb < 2; ++mb)
#pragma unroll
      for (int reg = 0; reg < 16; ++reg) {
        int row = mb * 32 + (reg & 3) + 8 * (reg >> 2) + 4 * hi;
        float y = acc[mb][reg] + bb[row];
        y = fmaxf(y, 0.f) + slope * fminf(y, 0.f);
        tl[wid][row][l31] = y * scl;
      }
  } else {
    float slope = aa[0];
#pragma unroll
    for (int mb = 0; mb < 2; ++mb)
#pragma unroll
      for (int reg = 0; reg < 16; ++reg) {
        int dv = (wid - 2) * 64 + mb * 32 + (reg & 3) + 8 * (reg >> 2) + 4 * hi;
        float y = acc[mb][reg] + ba[dv];
        y = fmaxf(y, 0.f) + slope * fminf(y, 0.f);
        vl[dv * 33 + l31] = y;
      }
  }
  __syncthreads();

  if (wid == 0) {                       // Q natural [s][64] bf16
    char* Qg = ws + Q_OFF + (size_t)n * (4096 * 128);
#pragma unroll
    for (int it = 0; it < 4; ++it) {
      int sl = (lane >> 3) + it * 8;
      u32x4 pv;
#pragma unroll
      for (int p = 0; p < 4; ++p)
        pv[p] = pack2(tl[0][(lane & 7) * 8 + 2 * p][sl],
                      tl[0][(lane & 7) * 8 + 2 * p + 1][sl]);
      *(u32x4*)(Qg + (size_t)(sb + sl) * 128 + (lane & 7) * 16) = pv;
    }
  } else if (wid == 1) {                // K fragment layout
    char* KFb = ws + KF_OFF + (size_t)n * (512 << 10);
    int d0 = (lane & 7) >> 1, hs = lane & 1;
#pragma unroll
    for (int it = 0; it < 4; ++it) {
      int sl = (lane >> 3) + it * 8;
      u32x4 pv;
#pragma unroll
      for (int p = 0; p < 4; ++p)
        pv[p] = pack2(tl[1][(lane & 7) * 8 + 2 * p][sl],
                      tl[1][(lane & 7) * 8 + 2 * p + 1][sl]);
      *(u32x4*)(KFb + ((size_t)(st * 4 + d0) * 64 + hs * 32 + sl) * 16) = pv;
    }
  }
  // all 256 threads: V fragment stores (512 units of 16B)
  {
    char* VFb = ws + VF_OFF + (size_t)n * (1u << 20);
#pragma unroll
    for (int r = 0; r < 2; ++r) {
      int u = tid + r * 256;
      int dv = u >> 2, sc = u & 3;
      u32x4 pv;
#pragma unroll
      for (int p = 0; p < 4; ++p)
        pv[p] = pack2(vl[dv * 33 + sc * 8 + 2 * p], vl[dv * 33 + sc * 8 + 2 * p + 1]);
      int unit = st * 8 + (dv >> 5) * 2 + (sc >> 1);
      *(u32x4*)(VFb + ((size_t)unit * 64 + (sc & 1) * 32 + (dv & 31)) * 16) = pv;
    }
  }
}

// -------- kernel 2: flash attention, in-block split-K, barrier-free loop ----
// 256 blocks: bid -> batch = bid&3 (one batch per XCD), qt = bid>>2 (0..63).
// Block owns q = qt*64..+64. Wave wid owns kv = wid*1024..+1024 (32 tiles).
// Per-wave private 3-buffer LDS pipeline (36KB each), NO barriers in loop:
//   {s_waitcnt vmcnt(12); stage(t+2); QK(t)+SM(t)+PV(t)}   (vmcnt(0) at end)
// Then 2 barriers: exchange partials via LDS, combine, write out.
__global__ __launch_bounds__(256, 1) void attn_kernel(char* __restrict__ ws,
                                                      float* __restrict__ out) {
  int bid = blockIdx.x;
  int batch = bid & 3;
  int qt = bid >> 2;                    // 0..63
  int tid = threadIdx.x;
  int wid = tid >> 6, lane = tid & 63, l31 = lane & 31, hi = lane >> 5;

  const char* Qb  = ws + Q_OFF  + (size_t)batch * (4096 * 128);
  const char* Kt0 = ws + KF_OFF + (size_t)batch * (512 << 10) +
                    (size_t)(wid * 32) * 4096;
  const char* Vt0 = ws + VF_OFF + (size_t)batch * (1u << 20) +
                    (size_t)(wid * 32) * 8192;

  __shared__ char sbuf[4][3][12288];    // per-wave private; reused for combine
  char* myb = &sbuf[wid][0][0];

  int q0 = qt * 64;
  int lo16 = lane * 16;

  bf16x8 qf0[4], qf1[4];                // Q frags for the block's 2 q-sets
#pragma unroll
  for (int d0 = 0; d0 < 4; ++d0) {
    qf0[d0] = *(const bf16x8*)(Qb + (size_t)(q0 + l31) * 128 + d0 * 32 + hi * 16);
    qf1[d0] = *(const bf16x8*)(Qb + (size_t)(q0 + 32 + l31) * 128 + d0 * 32 + hi * 16);
  }

  f32x16 oacc[2][4];
#pragma unroll
  for (int qs = 0; qs < 2; ++qs)
#pragma unroll
    for (int i = 0; i < 4; ++i) oacc[qs][i] = 0.f;
  float denA0 = 0.f, denA1 = 0.f, denB0 = 0.f, denB1 = 0.f;

  // stage one 32-kv tile (12 x 1KB chunks) into this wave's buffer b
  auto stage = [&](int b, int t) {
    char* dst = myb + b * 12288;
    const char* ks = Kt0 + (size_t)t * 4096;
    const char* vs = Vt0 + (size_t)t * 8192;
#pragma unroll
    for (int i = 0; i < 4; ++i) gld_lds16(ks + i * 1024 + lo16, dst + i * 1024);
#pragma unroll
    for (int i = 0; i < 8; ++i) gld_lds16(vs + i * 1024 + lo16,
                                          dst + 4096 + i * 1024);
  };

  stage(0, 0);                          // 12 outstanding (this wave)
  stage(1, 1);                          // 24 outstanding

  for (int t = 0; t < 32; ++t) {
    // self-paced: wait only tile t's 12 loads; t+1's stay in flight
    if (t < 31) asm volatile("s_waitcnt vmcnt(12)" ::: "memory");
    else        asm volatile("s_waitcnt vmcnt(0)" ::: "memory");

    if (t + 2 < 32) stage((t + 2) % 3, t + 2);   // overlaps this region

    const char* kb = myb + (t % 3) * 12288;
    const char* vb = kb + 4096;

    // QK both q-sets: S^T[k][q], k = (reg&3)+8*(reg>>2)+4*hi, q = l31
    f32x16 s0, s1;
    s0 = 0.f; s1 = 0.f;
#pragma unroll
    for (int d0 = 0; d0 < 4; ++d0) {
      bf16x8 kf = *(const bf16x8*)(kb + d0 * 1024 + lo16);
      s0 = __builtin_amdgcn_mfma_f32_32x32x16_bf16(kf, qf0[d0], s0, 0, 0, 0);
      s1 = __builtin_amdgcn_mfma_f32_32x32x16_bf16(kf, qf1[d0], s1, 0, 0, 0);
    }

    // softmax: p = exp2(s) (Q pre-scaled by log2e), unnormalized
    unsigned pk0[8], pk1[8];
#pragma unroll
    for (int m = 0; m < 8; ++m) {
      float a0 = __builtin_amdgcn_exp2f(s0[2 * m]);
      float a1 = __builtin_amdgcn_exp2f(s0[2 * m + 1]);
      if (m & 1) denA1 += a0 + a1; else denA0 += a0 + a1;
      pk0[m] = pack2(a0, a1);
      float b0 = __builtin_amdgcn_exp2f(s1[2 * m]);
      float b1 = __builtin_amdgcn_exp2f(s1[2 * m + 1]);
      if (m & 1) denB1 += b0 + b1; else denB0 += b0 + b1;
      pk1[m] = pack2(b0, b1);
    }

    // PV: O^T[dv][q] += V^T · P^T ; each vf read feeds both q-sets
#pragma unroll
    for (int kc = 0; kc < 2; ++kc) {
      const int bs = kc * 4;
      u32x2 r0 = __builtin_amdgcn_permlane32_swap(pk0[bs + 0], pk0[bs + 2],
                                                  false, false);
      u32x2 r1 = __builtin_amdgcn_permlane32_swap(pk0[bs + 1], pk0[bs + 3],
                                                  false, false);
      u32x4 pu0 = {r0.x, r1.x, r0.y, r1.y};
      bf16x8 pf0 = __builtin_bit_cast(bf16x8, pu0);
      u32x2 r2 = __builtin_amdgcn_permlane32_swap(pk1[bs + 0], pk1[bs + 2],
                                                  false, false);
      u32x2 r3 = __builtin_amdgcn_permlane32_swap(pk1[bs + 1], pk1[bs + 3],
                                                  false, false);
      u32x4 pu1 = {r2.x, r3.x, r2.y, r3.y};
      bf16x8 pf1 = __builtin_bit_cast(bf16x8, pu1);
#pragma unroll
      for (int dvb = 0; dvb < 4; ++dvb) {
        bf16x8 vf = *(const bf16x8*)(vb + (dvb * 2 + kc) * 1024 + lo16);
        oacc[0][dvb] = __builtin_amdgcn_mfma_f32_32x32x16_bf16(vf, pf0,
                                                               oacc[0][dvb], 0, 0, 0);
        oacc[1][dvb] = __builtin_amdgcn_mfma_f32_32x32x16_bf16(vf, pf1,
                                                               oacc[1][dvb], 0, 0, 0);
      }
    }
  }

  // ---- in-block combine: exchange partials through LDS (reuse sbuf) ----
  __syncthreads();                      // all waves done reading their staging

  unsigned short* pOP = (unsigned short*)&sbuf[0][0][0];  // [4][64 q][136] bf16
  float* pDEN = (float*)((char*)pOP + 4 * 64 * 136 * 2);  // [4][64] f32

#pragma unroll
  for (int qs = 0; qs < 2; ++qs) {
    int q = qs * 32 + l31;
#pragma unroll
    for (int dvb = 0; dvb < 4; ++dvb)
#pragma unroll
      for (int j = 0; j < 4; ++j) {     // regs 4j..4j+3 -> dv db..db+3
        int db = dvb * 32 + 8 * j + 4 * hi;
        u32x2 wv = { pack2(oacc[qs][dvb][4 * j],     oacc[qs][dvb][4 * j + 1]),
                     pack2(oacc[qs][dvb][4 * j + 2], oacc[qs][dvb][4 * j + 3]) };
        *(u32x2*)&pOP[(wid * 64 + q) * 136 + db] = wv;
      }
    float den = qs ? (denB0 + denB1) : (denA0 + denA1);
    float dtot = den + __shfl_xor(den, 32, 64);
    if (hi == 0) pDEN[wid * 64 + q] = dtot;
  }
  __syncthreads();

  {
    int q = tid & 63, dvg = tid >> 6;
    float dsum = (pDEN[q] + pDEN[64 + q]) + (pDEN[128 + q] + pDEN[192 + q]);
    float inv = 1.0f / dsum;
    float* og = out + (size_t)batch * 128 * 4096 + (size_t)qt * 64 + q;
#pragma unroll
    for (int it = 0; it < 4; ++it) {
      int dv = dvg * 32 + it * 8;
      float acc8[8] = {0.f, 0.f, 0.f, 0.f, 0.f, 0.f, 0.f, 0.f};
#pragma unroll
      for (int w = 0; w < 4; ++w) {     // fixed order -> deterministic
        bf16x8 v = *(const bf16x8*)&pOP[(w * 64 + q) * 136 + dv];
#pragma unroll
        for (int j = 0; j < 8; ++j) acc8[j] += (float)v[j];
      }
#pragma unroll
      for (int j = 0; j < 8; ++j)       // coalesced: lanes = consecutive q
        og[(size_t)(dv + j) * 4096] = acc8[j] * inv;
    }
  }
}

// ---------------------------------------------------------------------------
extern "C" void kernel_launch(void* const* d_in, const int* in_sizes, int n_in,
                              void* d_out, int out_size, void* d_ws, size_t ws_size,
                              hipStream_t stream) {
  (void)in_sizes; (void)n_in; (void)out_size; (void)ws_size;
  const float* x  = (const float*)d_in[0];
  const float* w1 = (const float*)d_in[1];
  const float* b1 = (const float*)d_in[2];
  const float* a1 = (const float*)d_in[3];
  const float* w2 = (const float*)d_in[4];
  const float* b2 = (const float*)d_in[5];
  const float* a2 = (const float*)d_in[6];
  const float* wa = (const float*)d_in[7];
  const float* ba = (const float*)d_in[8];
  const float* aa = (const float*)d_in[9];
  char* ws = (char*)d_ws;
  float* out = (float*)d_out;

  wcast_kernel<<<dim3(32), dim3(256), 0, stream>>>(w1, w2, wa, ws);
  conv_kernel<<<dim3(512), dim3(256), 0, stream>>>(x, ws, b1, a1, b2, a2, ba, aa);
  attn_kernel<<<dim3(256), dim3(256), 0, stream>>>(ws, out);
}

// Round 22
// 59.978 us; speedup vs baseline: 2.4763x; 1.0183x over previous
//
#include <hip/hip_runtime.h>
#include <hip/hip_bf16.h>
#include <stdint.h>

// ---------------------------------------------------------------------------
// MultiScaleAttention: x[4,128,4096] -> 3x conv1x1+PReLU -> attention -> out
//   conv (fused transpose): Q [n][s][64] bf16 (*log2e), K/V in MFMA-fragment-
//   ready GLOBAL layouts (1KB contiguous per wave-fragment). Split-bf16 MFMA.
//   attn: 512-thr blocks = 4 q-chunks x 2 kv-halves (8 waves, 2/SIMD ->
//   MFMA||VALU co-scheduling). Per-half 3-buffer LDS stream (72KB), T4
//   counted-vmcnt(3), 16 regions. kv-pair partials exchanged via LDS indexed
//   by FULL lane (bf16-packed, 64KB) -- fixes R21's hi-collision race.
//   OP/DEN keep the 4-split layout; combine kernel as R18.
// KF layout: [n][t(32k)][d0(4)][slot(64)]*16B, slot=hi*32+l31 ->
//            K[t*32+l31][d0*16+hi*8 ..+8]
// VF layout: [n][t(32k)][dvb*2+kc(8)][slot(64)]*16B, slot=hi*32+l31 ->
//            V^T[dvb*32+l31][t*32+kc*16+hi*8 ..+8]
// ---------------------------------------------------------------------------

typedef float   f32x16 __attribute__((ext_vector_type(16)));
typedef __bf16  bf16x8 __attribute__((ext_vector_type(8)));
typedef __bf16  bf16x2 __attribute__((ext_vector_type(2)));
typedef unsigned int u32x4 __attribute__((ext_vector_type(4)));
typedef unsigned int u32x2 __attribute__((ext_vector_type(2)));

#define L2E 1.4426950408889634f

// workspace layout (bytes); ws_size ~268MB
#define Q_OFF   (0u)                          // [4][4096][64] bf16 = 2MB
#define KF_OFF  (2u << 20)                    // frag-K, 512KB/batch = 2MB
#define VF_OFF  (4u << 20)                    // frag-V, 1MB/batch = 4MB
#define DEN_OFF (8u << 20)                    // [4][16][4][256] f32 = 256KB
#define WH_OFF  ((8u << 20) + (1u << 19))     // W hi bf16 [256][128] = 64KB
#define WL_OFF  (WH_OFF + (1u << 16))
#define OP_OFF  (9u << 20)                    // num bf16 [4][16][4][128][256] = 16.8MB

__device__ inline unsigned short f2bf(float f) {   // hw v_cvt (RNE)
  __bf16 h = (__bf16)f;
  return __builtin_bit_cast(unsigned short, h);
}
__device__ inline float bf2f(unsigned short h) {
  unsigned u = ((unsigned)h) << 16;
  return __builtin_bit_cast(float, u);
}
__device__ inline unsigned pack2(float a, float b) {   // v_cvt_pk_bf16_f32
  bf16x2 t = { (__bf16)a, (__bf16)b };
  return __builtin_bit_cast(unsigned, t);
}

__device__ inline void gld_lds16(const void* g, void* l) {
  __builtin_amdgcn_global_load_lds(
      (const __attribute__((address_space(1))) unsigned*)g,
      (__attribute__((address_space(3))) unsigned*)l, 16, 0, 0);
}

// --------------------------- kernel 0: cast weights ------------------------
__global__ void wcast_kernel(const float* __restrict__ w1, const float* __restrict__ w2,
                             const float* __restrict__ wa, char* __restrict__ ws) {
  int idx = blockIdx.x * 256 + threadIdx.x;   // 32 blocks
  unsigned short* WH = (unsigned short*)(ws + WH_OFF);
  unsigned short* WL = (unsigned short*)(ws + WL_OFF);
#pragma unroll
  for (int r = 0; r < 4; ++r) {
    int i = r * 8192 + idx;                   // 0..32767
    int oc = i >> 7, c = i & 127;
    float v = oc < 64 ? w1[oc * 128 + c]
            : (oc < 128 ? w2[(oc - 64) * 128 + c] : wa[(oc - 128) * 128 + c]);
    __bf16 h = (__bf16)v;
    WH[i] = __builtin_bit_cast(unsigned short, h);
    WL[i] = f2bf(v - (float)h);
  }
}

// ------- kernel 1: conv1x1 + bias + PReLU -> Q, KF, VF (fused transpose) ----
// 512 blocks = 4n * 128 s-tiles(32). Waves: 0->Q(*L2E), 1->K, 2,3->V.
__global__ __launch_bounds__(256) void conv_kernel(
    const float* __restrict__ x, char* __restrict__ ws,
    const float* __restrict__ b1, const float* __restrict__ a1,
    const float* __restrict__ b2, const float* __restrict__ a2,
    const float* __restrict__ ba, const float* __restrict__ aa) {
  int bid = blockIdx.x;
  int n = bid >> 7, st = bid & 127;           // st == kv tile index t
  int sb = st * 32;
  int tid = threadIdx.x;
  int wid = tid >> 6, lane = tid & 63, l31 = lane & 31, hi = lane >> 5;

  __shared__ float xl[128][36];         // x-tile transpose; later reused as vl
  __shared__ float tl[2][64][33];       // Q/K f32 transpose buffers
  float* vl = (float*)xl;               // [128][33] V f32, reuse after MFMA

  const float* xb = x + (size_t)n * 128 * 4096;
#pragma unroll
  for (int it = 0; it < 4; ++it) {      // load 128x32 f32 tile
    int flat4 = tid + 256 * it;
    int c = flat4 >> 3, s4 = flat4 & 7;
    float4 v = *(const float4*)(xb + (size_t)c * 4096 + sb + s4 * 4);
    *(float4*)&xl[c][s4 * 4] = v;
  }
  __syncthreads();

  const char* WH = ws + WH_OFF;
  const char* WL = ws + WL_OFF;
  int oc0 = wid * 64;

  f32x16 acc[2];
  acc[0] = 0.f; acc[1] = 0.f;
#pragma unroll
  for (int c0 = 0; c0 < 8; ++c0) {
    __bf16 eh[8], el[8];
#pragma unroll
    for (int j = 0; j < 8; ++j) {
      float v = xl[c0 * 16 + hi * 8 + j][l31];
      __bf16 h = (__bf16)v;
      eh[j] = h;
      el[j] = (__bf16)(v - (float)h);
    }
    bf16x8 xh = {eh[0], eh[1], eh[2], eh[3], eh[4], eh[5], eh[6], eh[7]};
    bf16x8 xlo = {el[0], el[1], el[2], el[3], el[4], el[5], el[6], el[7]};
#pragma unroll
    for (int mb = 0; mb < 2; ++mb) {
      size_t wo = (size_t)(oc0 + mb * 32 + l31) * 256 + c0 * 32 + hi * 16;
      bf16x8 wh = *(const bf16x8*)(WH + wo);
      bf16x8 wl = *(const bf16x8*)(WL + wo);
      acc[mb] = __builtin_amdgcn_mfma_f32_32x32x16_bf16(wh, xh, acc[mb], 0, 0, 0);
      acc[mb] = __builtin_amdgcn_mfma_f32_32x32x16_bf16(wh, xlo, acc[mb], 0, 0, 0);
      acc[mb] = __builtin_amdgcn_mfma_f32_32x32x16_bf16(wl, xh, acc[mb], 0, 0, 0);
    }
  }
  __syncthreads();                      // all waves done reading xl

  if (wid < 2) {
    const float* bb = wid ? b2 : b1;
    float slope = wid ? a2[0] : a1[0];
    float scl = wid ? 1.0f : L2E;       // fold softmax log2e into Q
#pragma unroll
    for (int mb = 0; mb < 2; ++mb)
#pragma unroll
      for (int reg = 0; reg < 16; ++reg) {
        int row = mb * 32 + (reg & 3) + 8 * (reg >> 2) + 4 * hi;
        float y = acc[mb][reg] + bb[row];
        y = fmaxf(y, 0.f) + slope * fminf(y, 0.f);
        tl[wid][row][l31] = y * scl;
      }
  } else {
    float slope = aa[0];
#pragma unroll
    for (int mb = 0; mb < 2; ++mb)
#pragma unroll
      for (int reg = 0; reg < 16; ++reg) {
        int dv = (wid - 2) * 64 + mb * 32 + (reg & 3) + 8 * (reg >> 2) + 4 * hi;
        float y = acc[mb][reg] + ba[dv];
        y = fmaxf(y, 0.f) + slope * fminf(y, 0.f);
        vl[dv * 33 + l31] = y;
      }
  }
  __syncthreads();

  if (wid == 0) {                       // Q natural [s][64] bf16
    char* Qg = ws + Q_OFF + (size_t)n * (4096 * 128);
#pragma unroll
    for (int it = 0; it < 4; ++it) {
      int sl = (lane >> 3) + it * 8;
      u32x4 pv;
#pragma unroll
      for (int p = 0; p < 4; ++p)
        pv[p] = pack2(tl[0][(lane & 7) * 8 + 2 * p][sl],
                      tl[0][(lane & 7) * 8 + 2 * p + 1][sl]);
      *(u32x4*)(Qg + (size_t)(sb + sl) * 128 + (lane & 7) * 16) = pv;
    }
  } else if (wid == 1) {                // K fragment layout
    char* KFb = ws + KF_OFF + (size_t)n * (512 << 10);
    int d0 = (lane & 7) >> 1, hs = lane & 1;
#pragma unroll
    for (int it = 0; it < 4; ++it) {
      int sl = (lane >> 3) + it * 8;
      u32x4 pv;
#pragma unroll
      for (int p = 0; p < 4; ++p)
        pv[p] = pack2(tl[1][(lane & 7) * 8 + 2 * p][sl],
                      tl[1][(lane & 7) * 8 + 2 * p + 1][sl]);
      *(u32x4*)(KFb + ((size_t)(st * 4 + d0) * 64 + hs * 32 + sl) * 16) = pv;
    }
  }
  // all 256 threads: V fragment stores (512 units of 16B)
  {
    char* VFb = ws + VF_OFF + (size_t)n * (1u << 20);
#pragma unroll
    for (int r = 0; r < 2; ++r) {
      int u = tid + r * 256;
      int dv = u >> 2, sc = u & 3;
      u32x4 pv;
#pragma unroll
      for (int p = 0; p < 4; ++p)
        pv[p] = pack2(vl[dv * 33 + sc * 8 + 2 * p], vl[dv * 33 + sc * 8 + 2 * p + 1]);
      int unit = st * 8 + (dv >> 5) * 2 + (sc >> 1);
      *(u32x4*)(VFb + ((size_t)unit * 64 + (sc & 1) * 32 + (dv & 31)) * 16) = pv;
    }
  }
}

// --------------------------- kernel 2: flash attention ----------------------
// 256 blocks x 512 threads: bid -> split(4) | qt(16) | batch(4). 1 block/CU,
// 8 waves = 4 q-chunks x 2 kv-halves -> 2 waves/SIMD (MFMA||VALU overlap).
// Per-half 3-buffer LDS stream; region:
//   {s_waitcnt vmcnt(3); s_barrier; stage(t+2); QK(t)+SM(t)+PV(t)}  x16.
// End: kv-pair reduction via LDS indexed by FULL lane (bf16-packed);
// kvh=0 waves write OP/DEN (4-split layout, combine as R18).
__global__ __launch_bounds__(512, 1) void attn_kernel(char* __restrict__ ws) {
  int bid = blockIdx.x;
  int split = bid & 3;
  int qt = (bid >> 2) & 15;
  int batch = bid >> 6;
  int tid = threadIdx.x;
  int wid = tid >> 6;                   // 0..7
  int kvh = wid & 1, qc = wid >> 1;     // kv half, q chunk
  int lane = tid & 63, l31 = lane & 31, hi = lane >> 5;

  const char* Qb  = ws + Q_OFF  + (size_t)batch * (4096 * 128);
  const char* Kt0 = ws + KF_OFF + (size_t)batch * (512 << 10) +
                    (size_t)(split * 32 + kvh * 16) * 4096;
  const char* Vt0 = ws + VF_OFF + (size_t)batch * (1u << 20) +
                    (size_t)(split * 32 + kvh * 16) * 8192;

  __shared__ __align__(16) char sbuf[2][3][12288];  // per-half streams; 72KB
  char* myb = &sbuf[kvh][0][0];

  int q0 = qt * 256 + qc * 64;
  int lo16 = lane * 16;

  bf16x8 qf0[4], qf1[4];                // Q frags for the wave's 2 q-sets
#pragma unroll
  for (int d0 = 0; d0 < 4; ++d0) {
    qf0[d0] = *(const bf16x8*)(Qb + (size_t)(q0 + l31) * 128 + d0 * 32 + hi * 16);
    qf1[d0] = *(const bf16x8*)(Qb + (size_t)(q0 + 32 + l31) * 128 + d0 * 32 + hi * 16);
  }

  f32x16 oacc[2][4];
#pragma unroll
  for (int qs = 0; qs < 2; ++qs)
#pragma unroll
    for (int i = 0; i < 4; ++i) oacc[qs][i] = 0.f;
  float denA0 = 0.f, denA1 = 0.f, denB0 = 0.f, denB1 = 0.f;

  // 12 chunks/tile staged by the 4 waves of this kv-half (3 each, by qc)
  auto stage = [&](int b, int t) {
#pragma unroll
    for (int i = 0; i < 3; ++i) {
      int c = qc * 3 + i;
      const char* src = (c < 4) ? Kt0 + (size_t)t * 4096 + c * 1024 + lo16
                                : Vt0 + (size_t)t * 8192 + (c - 4) * 1024 + lo16;
      gld_lds16(src, &myb[b * 12288 + c * 1024]);
    }
  };

  stage(0, 0);                          // 3 outstanding (this wave)
  stage(1, 1);                          // 6 outstanding

  for (int t = 0; t < 16; ++t) {
    // wait ONLY for tile t's 3 loads (issued 2 regions ago); t+1's in flight
    if (t < 15) asm volatile("s_waitcnt vmcnt(3)" ::: "memory");
    else        asm volatile("s_waitcnt vmcnt(0)" ::: "memory");
    __builtin_amdgcn_s_barrier();       // raw: no drain; all waves' chunks in

    if (t + 2 < 16) stage((t + 2) % 3, t + 2);   // overlaps this region

    const char* kb = myb + (t % 3) * 12288;
    const char* vb = kb + 4096;

    // QK both q-sets: S^T[k][q], k = (reg&3)+8*(reg>>2)+4*hi, q = l31
    f32x16 s0, s1;
    s0 = 0.f; s1 = 0.f;
#pragma unroll
    for (int d0 = 0; d0 < 4; ++d0) {
      bf16x8 kf = *(const bf16x8*)(kb + d0 * 1024 + lo16);
      s0 = __builtin_amdgcn_mfma_f32_32x32x16_bf16(kf, qf0[d0], s0, 0, 0, 0);
      s1 = __builtin_amdgcn_mfma_f32_32x32x16_bf16(kf, qf1[d0], s1, 0, 0, 0);
    }

    // softmax: p = exp2(s) (Q pre-scaled by log2e), unnormalized
    unsigned pk0[8], pk1[8];
#pragma unroll
    for (int m = 0; m < 8; ++m) {
      float a0 = __builtin_amdgcn_exp2f(s0[2 * m]);
      float a1 = __builtin_amdgcn_exp2f(s0[2 * m + 1]);
      if (m & 1) denA1 += a0 + a1; else denA0 += a0 + a1;
      pk0[m] = pack2(a0, a1);
      float b0 = __builtin_amdgcn_exp2f(s1[2 * m]);
      float b1 = __builtin_amdgcn_exp2f(s1[2 * m + 1]);
      if (m & 1) denB1 += b0 + b1; else denB0 += b0 + b1;
      pk1[m] = pack2(b0, b1);
    }

    // PV: O^T[dv][q] += V^T · P^T ; each vf read feeds both q-sets
#pragma unroll
    for (int kc = 0; kc < 2; ++kc) {
      const int bs = kc * 4;
      u32x2 r0 = __builtin_amdgcn_permlane32_swap(pk0[bs + 0], pk0[bs + 2],
                                                  false, false);
      u32x2 r1 = __builtin_amdgcn_permlane32_swap(pk0[bs + 1], pk0[bs + 3],
                                                  false, false);
      u32x4 pu0 = {r0.x, r1.x, r0.y, r1.y};
      bf16x8 pf0 = __builtin_bit_cast(bf16x8, pu0);
      u32x2 r2 = __builtin_amdgcn_permlane32_swap(pk1[bs + 0], pk1[bs + 2],
                                                  false, false);
      u32x2 r3 = __builtin_amdgcn_permlane32_swap(pk1[bs + 1], pk1[bs + 3],
                                                  false, false);
      u32x4 pu1 = {r2.x, r3.x, r2.y, r3.y};
      bf16x8 pf1 = __builtin_bit_cast(bf16x8, pu1);
#pragma unroll
      for (int dvb = 0; dvb < 4; ++dvb) {
        bf16x8 vf = *(const bf16x8*)(vb + (dvb * 2 + kc) * 1024 + lo16);
        oacc[0][dvb] = __builtin_amdgcn_mfma_f32_32x32x16_bf16(vf, pf0,
                                                               oacc[0][dvb], 0, 0, 0);
        oacc[1][dvb] = __builtin_amdgcn_mfma_f32_32x32x16_bf16(vf, pf1,
                                                               oacc[1][dvb], 0, 0, 0);
      }
    }
    // no trailing barrier: next region's top barrier provides WAR safety
  }

  // ---- kv-pair reduction via LDS, indexed by FULL lane (race-free) ----
  float myden[2] = {denA0 + denA1, denB0 + denB1};
#pragma unroll
  for (int qs = 0; qs < 2; ++qs)
    myden[qs] += __shfl_xor(myden[qs], 32, 64);

  __syncthreads();                      // all staging reads done; reuse sbuf
  u32x2* xch = (u32x2*)&sbuf[0][0][0];  // [128 idx][64 lanes] u32x2 = 64KB
  float* denx = (float*)((char*)xch + 65536);        // [8][64] f32 = 2KB

  if (kvh == 1) {
#pragma unroll
    for (int qs = 0; qs < 2; ++qs) {
#pragma unroll
      for (int dvb = 0; dvb < 4; ++dvb)
#pragma unroll
        for (int j = 0; j < 4; ++j) {
          int idx = ((qc * 2 + qs) * 4 + dvb) * 4 + j;
          u32x2 wv = { pack2(oacc[qs][dvb][4 * j],     oacc[qs][dvb][4 * j + 1]),
                       pack2(oacc[qs][dvb][4 * j + 2], oacc[qs][dvb][4 * j + 3]) };
          xch[idx * 64 + lane] = wv;
        }
      denx[(qc * 2 + qs) * 64 + lane] = myden[qs];
    }
  }
  __syncthreads();

  if (kvh == 0) {
    int grp = batch * 16 + qt;
    unsigned short* OPu = (unsigned short*)(ws + OP_OFF) +
                          (size_t)(grp * 4 + split) * 32768;
    float* DEN = (float*)(ws + DEN_OFF) + (size_t)(grp * 4 + split) * 256;
#pragma unroll
    for (int qs = 0; qs < 2; ++qs) {
#pragma unroll
      for (int dvb = 0; dvb < 4; ++dvb)
#pragma unroll
        for (int j = 0; j < 4; ++j) {
          int idx = ((qc * 2 + qs) * 4 + dvb) * 4 + j;
          u32x2 wv = xch[idx * 64 + lane];
          oacc[qs][dvb][4 * j]     += bf2f((unsigned short)(wv.x & 0xffffu));
          oacc[qs][dvb][4 * j + 1] += bf2f((unsigned short)(wv.x >> 16));
          oacc[qs][dvb][4 * j + 2] += bf2f((unsigned short)(wv.y & 0xffffu));
          oacc[qs][dvb][4 * j + 3] += bf2f((unsigned short)(wv.y >> 16));
        }
      int qloc = qc * 64 + qs * 32 + l31;
#pragma unroll
      for (int dvb = 0; dvb < 4; ++dvb)
#pragma unroll
        for (int reg = 0; reg < 16; ++reg) {
          int dv = dvb * 32 + (reg & 3) + 8 * (reg >> 2) + 4 * hi;
          OPu[dv * 256 + qloc] = f2bf(oacc[qs][dvb][reg]);
        }
      if (hi == 0)
        DEN[qloc] = myden[qs] + denx[(qc * 2 + qs) * 64 + lane];
    }
  }
}

// --------------------------- kernel 3: combine splits -----------------------
// 1024 blocks; each thread produces 8 consecutive outputs (vectorized loads).
__global__ __launch_bounds__(256) void combine_kernel(const char* __restrict__ ws,
                                                      float* __restrict__ out) {
  int idx8 = (blockIdx.x * 256 + threadIdx.x) * 8;  // 2^21 outputs [n][c][s]
  int n = idx8 >> 19;
  int dv = (idx8 >> 12) & 127;
  int s0 = idx8 & 4095;                 // 8-aligned
  int qt = s0 >> 8, ql = s0 & 255;
  const unsigned short* OPu = (const unsigned short*)(ws + OP_OFF);
  const float* DEN = (const float*)(ws + DEN_OFF);
  size_t pb = (size_t)((n * 16 + qt) * 4);
  float num[8], den[8];
#pragma unroll
  for (int j = 0; j < 8; ++j) { num[j] = 0.f; den[j] = 0.f; }
#pragma unroll
  for (int h = 0; h < 4; ++h) {
    bf16x8 v = *(const bf16x8*)(OPu + (pb + h) * 32768 + (size_t)dv * 256 + ql);
    const float* dp = DEN + (pb + h) * 256 + ql;
    float4 d0 = *(const float4*)dp;
    float4 d1 = *(const float4*)(dp + 4);
#pragma unroll
    for (int j = 0; j < 8; ++j) num[j] += (float)v[j];
    den[0] += d0.x; den[1] += d0.y; den[2] += d0.z; den[3] += d0.w;
    den[4] += d1.x; den[5] += d1.y; den[6] += d1.z; den[7] += d1.w;
  }
  float4 o0 = {num[0] / den[0], num[1] / den[1], num[2] / den[2], num[3] / den[3]};
  float4 o1 = {num[4] / den[4], num[5] / den[5], num[6] / den[6], num[7] / den[7]};
  *(float4*)&out[idx8] = o0;
  *(float4*)&out[idx8 + 4] = o1;
}

// ---------------------------------------------------------------------------
extern "C" void kernel_launch(void* const* d_in, const int* in_sizes, int n_in,
                              void* d_out, int out_size, void* d_ws, size_t ws_size,
                              hipStream_t stream) {
  (void)in_sizes; (void)n_in; (void)out_size; (void)ws_size;
  const float* x  = (const float*)d_in[0];
  const float* w1 = (const float*)d_in[1];
  const float* b1 = (const float*)d_in[2];
  const float* a1 = (const float*)d_in[3];
  const float* w2 = (const float*)d_in[4];
  const float* b2 = (const float*)d_in[5];
  const float* a2 = (const float*)d_in[6];
  const float* wa = (const float*)d_in[7];
  const float* ba = (const float*)d_in[8];
  const float* aa = (const float*)d_in[9];
  char* ws = (char*)d_ws;
  float* out = (float*)d_out;

  wcast_kernel<<<dim3(32), dim3(256), 0, stream>>>(w1, w2, wa, ws);
  conv_kernel<<<dim3(512), dim3(256), 0, stream>>>(x, ws, b1, a1, b2, a2, ba, aa);
  attn_kernel<<<dim3(256), dim3(512), 0, stream>>>(ws);
  combine_kernel<<<dim3(1024), dim3(256), 0, stream>>>(ws, out);
}

// Round 24
// 59.382 us; speedup vs baseline: 2.5011x; 1.0100x over previous
//
#include <hip/hip_runtime.h>
#include <hip/hip_bf16.h>
#include <stdint.h>

// ---------------------------------------------------------------------------
// MultiScaleAttention: x[4,128,4096] -> 3x conv1x1+PReLU -> attention -> out
//   conv (fused transpose): Q [n][s][64] bf16 (*log2e), K/V in MFMA-fragment-
//   ready GLOBAL layouts (1KB contiguous per wave-fragment -> linear LDS
//   staging, zero bank conflicts). Split-bf16 MFMA for fp32-level accuracy.
//   attn: q=64/wave (q=256/block), KVBLK=32, 3-buffer LDS, T4 counted-vmcnt;
//   4 kv-splits (grid 256 = 1 block/CU; halves OP round-trip vs 8 splits).
//   p = exp2(S^T) unnormalized; num bf16 + den f32 partials; combine divides.
// KF layout: [n][t(32k)][d0(4)][slot(64)]*16B, slot=hi*32+l31 ->
//            K[t*32+l31][d0*16+hi*8 ..+8]
// VF layout: [n][t(32k)][dvb*2+kc(8)][slot(64)]*16B, slot=hi*32+l31 ->
//            V^T[dvb*32+l31][t*32+kc*16+hi*8 ..+8]
// ---------------------------------------------------------------------------

typedef float   f32x16 __attribute__((ext_vector_type(16)));
typedef __bf16  bf16x8 __attribute__((ext_vector_type(8)));
typedef __bf16  bf16x2 __attribute__((ext_vector_type(2)));
typedef unsigned int u32x4 __attribute__((ext_vector_type(4)));
typedef unsigned int u32x2 __attribute__((ext_vector_type(2)));

#define L2E 1.4426950408889634f

// workspace layout (bytes); ws_size ~268MB
#define Q_OFF   (0u)                          // [4][4096][64] bf16 = 2MB
#define KF_OFF  (2u << 20)                    // frag-K, 512KB/batch = 2MB
#define VF_OFF  (4u << 20)                    // frag-V, 1MB/batch = 4MB
#define DEN_OFF (8u << 20)                    // [4][16][4][256] f32 = 256KB
#define WH_OFF  ((8u << 20) + (1u << 19))     // W hi bf16 [256][128] = 64KB
#define WL_OFF  (WH_OFF + (1u << 16))
#define OP_OFF  (9u << 20)                    // num bf16 [4][16][4][128][256] = 16.8MB

__device__ inline unsigned short f2bf(float f) {   // hw v_cvt (RNE)
  __bf16 h = (__bf16)f;
  return __builtin_bit_cast(unsigned short, h);
}
__device__ inline float bf2f(unsigned short h) {
  unsigned u = ((unsigned)h) << 16;
  return __builtin_bit_cast(float, u);
}
__device__ inline unsigned pack2(float a, float b) {   // v_cvt_pk_bf16_f32
  bf16x2 t = { (__bf16)a, (__bf16)b };
  return __builtin_bit_cast(unsigned, t);
}

__device__ inline void gld_lds16(const void* g, void* l) {
  __builtin_amdgcn_global_load_lds(
      (const __attribute__((address_space(1))) unsigned*)g,
      (__attribute__((address_space(3))) unsigned*)l, 16, 0, 0);
}

// --------------------------- kernel 0: cast weights ------------------------
__global__ void wcast_kernel(const float* __restrict__ w1, const float* __restrict__ w2,
                             const float* __restrict__ wa, char* __restrict__ ws) {
  int idx = blockIdx.x * 256 + threadIdx.x;   // 32 blocks
  unsigned short* WH = (unsigned short*)(ws + WH_OFF);
  unsigned short* WL = (unsigned short*)(ws + WL_OFF);
#pragma unroll
  for (int r = 0; r < 4; ++r) {
    int i = r * 8192 + idx;                   // 0..32767
    int oc = i >> 7, c = i & 127;
    float v = oc < 64 ? w1[oc * 128 + c]
            : (oc < 128 ? w2[(oc - 64) * 128 + c] : wa[(oc - 128) * 128 + c]);
    __bf16 h = (__bf16)v;
    WH[i] = __builtin_bit_cast(unsigned short, h);
    WL[i] = f2bf(v - (float)h);
  }
}

// ------- kernel 1: conv1x1 + bias + PReLU -> Q, KF, VF (fused transpose) ----
// 512 blocks = 4n * 128 s-tiles(32). Waves: 0->Q(*L2E), 1->K, 2,3->V.
__global__ __launch_bounds__(256) void conv_kernel(
    const float* __restrict__ x, char* __restrict__ ws,
    const float* __restrict__ b1, const float* __restrict__ a1,
    const float* __restrict__ b2, const float* __restrict__ a2,
    const float* __restrict__ ba, const float* __restrict__ aa) {
  int bid = blockIdx.x;
  int n = bid >> 7, st = bid & 127;           // st == kv tile index t
  int sb = st * 32;
  int tid = threadIdx.x;
  int wid = tid >> 6, lane = tid & 63, l31 = lane & 31, hi = lane >> 5;

  __shared__ float xl[128][36];         // x-tile transpose; later reused as vl
  __shared__ float tl[2][64][33];       // Q/K f32 transpose buffers
  float* vl = (float*)xl;               // [128][33] V f32, reuse after MFMA

  const float* xb = x + (size_t)n * 128 * 4096;
#pragma unroll
  for (int it = 0; it < 4; ++it) {      // load 128x32 f32 tile
    int flat4 = tid + 256 * it;
    int c = flat4 >> 3, s4 = flat4 & 7;
    float4 v = *(const float4*)(xb + (size_t)c * 4096 + sb + s4 * 4);
    *(float4*)&xl[c][s4 * 4] = v;
  }
  __syncthreads();

  const char* WH = ws + WH_OFF;
  const char* WL = ws + WL_OFF;
  int oc0 = wid * 64;

  f32x16 acc[2];
  acc[0] = 0.f; acc[1] = 0.f;
#pragma unroll
  for (int c0 = 0; c0 < 8; ++c0) {
    __bf16 eh[8], el[8];
#pragma unroll
    for (int j = 0; j < 8; ++j) {
      float v = xl[c0 * 16 + hi * 8 + j][l31];
      __bf16 h = (__bf16)v;
      eh[j] = h;
      el[j] = (__bf16)(v - (float)h);
    }
    bf16x8 xh = {eh[0], eh[1], eh[2], eh[3], eh[4], eh[5], eh[6], eh[7]};
    bf16x8 xlo = {el[0], el[1], el[2], el[3], el[4], el[5], el[6], el[7]};
#pragma unroll
    for (int mb = 0; mb < 2; ++mb) {
      size_t wo = (size_t)(oc0 + mb * 32 + l31) * 256 + c0 * 32 + hi * 16;
      bf16x8 wh = *(const bf16x8*)(WH + wo);
      bf16x8 wl = *(const bf16x8*)(WL + wo);
      acc[mb] = __builtin_amdgcn_mfma_f32_32x32x16_bf16(wh, xh, acc[mb], 0, 0, 0);
      acc[mb] = __builtin_amdgcn_mfma_f32_32x32x16_bf16(wh, xlo, acc[mb], 0, 0, 0);
      acc[mb] = __builtin_amdgcn_mfma_f32_32x32x16_bf16(wl, xh, acc[mb], 0, 0, 0);
    }
  }
  __syncthreads();                      // all waves done reading xl

  if (wid < 2) {
    const float* bb = wid ? b2 : b1;
    float slope = wid ? a2[0] : a1[0];
    float scl = wid ? 1.0f : L2E;       // fold softmax log2e into Q
#pragma unroll
    for (int mb = 0; mb < 2; ++mb)
#pragma unroll
      for (int reg = 0; reg < 16; ++reg) {
        int row = mb * 32 + (reg & 3) + 8 * (reg >> 2) + 4 * hi;
        float y = acc[mb][reg] + bb[row];
        y = fmaxf(y, 0.f) + slope * fminf(y, 0.f);
        tl[wid][row][l31] = y * scl;
      }
  } else {
    float slope = aa[0];
#pragma unroll
    for (int mb = 0; mb < 2; ++mb)
#pragma unroll
      for (int reg = 0; reg < 16; ++reg) {
        int dv = (wid - 2) * 64 + mb * 32 + (reg & 3) + 8 * (reg >> 2) + 4 * hi;
        float y = acc[mb][reg] + ba[dv];
        y = fmaxf(y, 0.f) + slope * fminf(y, 0.f);
        vl[dv * 33 + l31] = y;
      }
  }
  __syncthreads();

  if (wid == 0) {                       // Q natural [s][64] bf16
    char* Qg = ws + Q_OFF + (size_t)n * (4096 * 128);
#pragma unroll
    for (int it = 0; it < 4; ++it) {
      int sl = (lane >> 3) + it * 8;
      u32x4 pv;
#pragma unroll
      for (int p = 0; p < 4; ++p)
        pv[p] = pack2(tl[0][(lane & 7) * 8 + 2 * p][sl],
                      tl[0][(lane & 7) * 8 + 2 * p + 1][sl]);
      *(u32x4*)(Qg + (size_t)(sb + sl) * 128 + (lane & 7) * 16) = pv;
    }
  } else if (wid == 1) {                // K fragment layout
    char* KFb = ws + KF_OFF + (size_t)n * (512 << 10);
    int d0 = (lane & 7) >> 1, hs = lane & 1;
#pragma unroll
    for (int it = 0; it < 4; ++it) {
      int sl = (lane >> 3) + it * 8;
      u32x4 pv;
#pragma unroll
      for (int p = 0; p < 4; ++p)
        pv[p] = pack2(tl[1][(lane & 7) * 8 + 2 * p][sl],
                      tl[1][(lane & 7) * 8 + 2 * p + 1][sl]);
      *(u32x4*)(KFb + ((size_t)(st * 4 + d0) * 64 + hs * 32 + sl) * 16) = pv;
    }
  }
  // all 256 threads: V fragment stores (512 units of 16B)
  {
    char* VFb = ws + VF_OFF + (size_t)n * (1u << 20);
#pragma unroll
    for (int r = 0; r < 2; ++r) {
      int u = tid + r * 256;
      int dv = u >> 2, sc = u & 3;
      u32x4 pv;
#pragma unroll
      for (int p = 0; p < 4; ++p)
        pv[p] = pack2(vl[dv * 33 + sc * 8 + 2 * p], vl[dv * 33 + sc * 8 + 2 * p + 1]);
      int unit = st * 8 + (dv >> 5) * 2 + (sc >> 1);
      *(u32x4*)(VFb + ((size_t)unit * 64 + (sc & 1) * 32 + (dv & 31)) * 16) = pv;
    }
  }
}

// --------------------------- kernel 2: flash attention ----------------------
// 256 blocks: bid = ((batch*16+qt)<<2)|split -> 1 block/CU exactly.
// Block = 4 waves * 64 q = 256 q; kv = split*1024..+1024 (32 tiles of 32).
// 3-buffer LDS (36KB), stage distance 2; region:
//   {s_waitcnt vmcnt(3); s_barrier; stage(t+2); QK(t)+SM(t)+PV(t)}
__global__ __launch_bounds__(256, 2) void attn_kernel(char* __restrict__ ws) {
  int bid = blockIdx.x;
  int split = bid & 3;
  int qt = (bid >> 2) & 15;
  int batch = bid >> 6;
  int tid = threadIdx.x;
  int wid = tid >> 6, lane = tid & 63, l31 = lane & 31, hi = lane >> 5;

  const char* Qb  = ws + Q_OFF  + (size_t)batch * (4096 * 128);
  const char* Kt0 = ws + KF_OFF + (size_t)batch * (512 << 10) +
                    (size_t)(split * 32) * 4096;
  const char* Vt0 = ws + VF_OFF + (size_t)batch * (1u << 20) +
                    (size_t)(split * 32) * 8192;

  __shared__ char sbuf[3][12288];       // [0,4K)=K tile, [4K,12K)=V tile

  int q0 = qt * 256 + wid * 64;
  int lo16 = lane * 16;

  bf16x8 qf0[4], qf1[4];                // Q frags for the wave's 2 q-sets
#pragma unroll
  for (int d0 = 0; d0 < 4; ++d0) {
    qf0[d0] = *(const bf16x8*)(Qb + (size_t)(q0 + l31) * 128 + d0 * 32 + hi * 16);
    qf1[d0] = *(const bf16x8*)(Qb + (size_t)(q0 + 32 + l31) * 128 + d0 * 32 + hi * 16);
  }

  f32x16 oacc[2][4];
#pragma unroll
  for (int qs = 0; qs < 2; ++qs)
#pragma unroll
    for (int i = 0; i < 4; ++i) oacc[qs][i] = 0.f;
  float denA0 = 0.f, denA1 = 0.f, denB0 = 0.f, denB1 = 0.f;

  // each wave stages 3 of the 12 1KB chunks (K: c<4, V: c>=4)
  auto stage = [&](int b, int t) {
#pragma unroll
    for (int i = 0; i < 3; ++i) {
      int c = wid * 3 + i;
      const char* src = (c < 4) ? Kt0 + (size_t)t * 4096 + c * 1024 + lo16
                                : Vt0 + (size_t)t * 8192 + (c - 4) * 1024 + lo16;
      gld_lds16(src, &sbuf[b][c * 1024]);
    }
  };

  stage(0, 0);                          // 3 outstanding (this wave)
  stage(1, 1);                          // 6 outstanding

  for (int t = 0; t < 32; ++t) {
    // wait ONLY for tile t's 3 loads (issued 2 regions ago); t+1's in flight
    if (t < 31) asm volatile("s_waitcnt vmcnt(3)" ::: "memory");
    else        asm volatile("s_waitcnt vmcnt(0)" ::: "memory");
    __builtin_amdgcn_s_barrier();       // raw: no drain; all waves' chunks in

    if (t + 2 < 32) stage((t + 2) % 3, t + 2);   // overlaps this region

    const char* kb = sbuf[t % 3];
    const char* vb = kb + 4096;

    // QK both q-sets: S^T[k][q], k = (reg&3)+8*(reg>>2)+4*hi, q = l31
    f32x16 s0, s1;
    s0 = 0.f; s1 = 0.f;
#pragma unroll
    for (int d0 = 0; d0 < 4; ++d0) {
      bf16x8 kf = *(const bf16x8*)(kb + d0 * 1024 + lo16);
      s0 = __builtin_amdgcn_mfma_f32_32x32x16_bf16(kf, qf0[d0], s0, 0, 0, 0);
      s1 = __builtin_amdgcn_mfma_f32_32x32x16_bf16(kf, qf1[d0], s1, 0, 0, 0);
    }

    // softmax: p = exp2(s) (Q pre-scaled by log2e), unnormalized
    unsigned pk0[8], pk1[8];
#pragma unroll
    for (int m = 0; m < 8; ++m) {
      float a0 = __builtin_amdgcn_exp2f(s0[2 * m]);
      float a1 = __builtin_amdgcn_exp2f(s0[2 * m + 1]);
      if (m & 1) denA1 += a0 + a1; else denA0 += a0 + a1;
      pk0[m] = pack2(a0, a1);
      float b0 = __builtin_amdgcn_exp2f(s1[2 * m]);
      float b1 = __builtin_amdgcn_exp2f(s1[2 * m + 1]);
      if (m & 1) denB1 += b0 + b1; else denB0 += b0 + b1;
      pk1[m] = pack2(b0, b1);
    }

    // PV: O^T[dv][q] += V^T · P^T ; each vf read feeds both q-sets
#pragma unroll
    for (int kc = 0; kc < 2; ++kc) {
      const int bs = kc * 4;
      u32x2 r0 = __builtin_amdgcn_permlane32_swap(pk0[bs + 0], pk0[bs + 2],
                                                  false, false);
      u32x2 r1 = __builtin_amdgcn_permlane32_swap(pk0[bs + 1], pk0[bs + 3],
                                                  false, false);
      u32x4 pu0 = {r0.x, r1.x, r0.y, r1.y};
      bf16x8 pf0 = __builtin_bit_cast(bf16x8, pu0);
      u32x2 r2 = __builtin_amdgcn_permlane32_swap(pk1[bs + 0], pk1[bs + 2],
                                                  false, false);
      u32x2 r3 = __builtin_amdgcn_permlane32_swap(pk1[bs + 1], pk1[bs + 3],
                                                  false, false);
      u32x4 pu1 = {r2.x, r3.x, r2.y, r3.y};
      bf16x8 pf1 = __builtin_bit_cast(bf16x8, pu1);
#pragma unroll
      for (int dvb = 0; dvb < 4; ++dvb) {
        bf16x8 vf = *(const bf16x8*)(vb + (dvb * 2 + kc) * 1024 + lo16);
        oacc[0][dvb] = __builtin_amdgcn_mfma_f32_32x32x16_bf16(vf, pf0,
                                                               oacc[0][dvb], 0, 0, 0);
        oacc[1][dvb] = __builtin_amdgcn_mfma_f32_32x32x16_bf16(vf, pf1,
                                                               oacc[1][dvb], 0, 0, 0);
      }
    }
    // no trailing barrier: next region's top barrier provides WAR safety
  }

  // write numerator partials (bf16, cacheable -> L2/L3 for combine) + den
  unsigned short* OPu = (unsigned short*)(ws + OP_OFF) +
                        (size_t)((batch * 16 + qt) * 4 + split) * 32768;
#pragma unroll
  for (int qs = 0; qs < 2; ++qs) {
    int qloc = wid * 64 + qs * 32 + l31;
#pragma unroll
    for (int dvb = 0; dvb < 4; ++dvb)
#pragma unroll
      for (int reg = 0; reg < 16; ++reg) {
        int dv = dvb * 32 + (reg & 3) + 8 * (reg >> 2) + 4 * hi;
        OPu[dv * 256 + qloc] = f2bf(oacc[qs][dvb][reg]);
      }
    float den = qs ? (denB0 + denB1) : (denA0 + denA1);
    float dtot = den + __shfl_xor(den, 32, 64);
    if (hi == 0) {
      float* DEN = (float*)(ws + DEN_OFF) +
                   (size_t)((batch * 16 + qt) * 4 + split) * 256;
      DEN[qloc] = dtot;
    }
  }
}

// --------------------------- kernel 3: combine splits -----------------------
// 1024 blocks; each thread produces 8 consecutive outputs (vectorized loads).
__global__ __launch_bounds__(256) void combine_kernel(const char* __restrict__ ws,
                                                      float* __restrict__ out) {
  int idx8 = (blockIdx.x * 256 + threadIdx.x) * 8;  // 2^21 outputs [n][c][s]
  int n = idx8 >> 19;
  int dv = (idx8 >> 12) & 127;
  int s0 = idx8 & 4095;                 // 8-aligned
  int qt = s0 >> 8, ql = s0 & 255;
  const unsigned short* OPu = (const unsigned short*)(ws + OP_OFF);
  const float* DEN = (const float*)(ws + DEN_OFF);
  size_t pb = (size_t)((n * 16 + qt) * 4);
  float num[8], den[8];
#pragma unroll
  for (int j = 0; j < 8; ++j) { num[j] = 0.f; den[j] = 0.f; }
#pragma unroll
  for (int h = 0; h < 4; ++h) {
    bf16x8 v = *(const bf16x8*)(OPu + (pb + h) * 32768 + (size_t)dv * 256 + ql);
    const float* dp = DEN + (pb + h) * 256 + ql;
    float4 d0 = *(const float4*)dp;
    float4 d1 = *(const float4*)(dp + 4);
#pragma unroll
    for (int j = 0; j < 8; ++j) num[j] += (float)v[j];
    den[0] += d0.x; den[1] += d0.y; den[2] += d0.z; den[3] += d0.w;
    den[4] += d1.x; den[5] += d1.y; den[6] += d1.z; den[7] += d1.w;
  }
  float4 o0 = {num[0] / den[0], num[1] / den[1], num[2] / den[2], num[3] / den[3]};
  float4 o1 = {num[4] / den[4], num[5] / den[5], num[6] / den[6], num[7] / den[7]};
  *(float4*)&out[idx8] = o0;
  *(float4*)&out[idx8 + 4] = o1;
}

// ---------------------------------------------------------------------------
extern "C" void kernel_launch(void* const* d_in, const int* in_sizes, int n_in,
                              void* d_out, int out_size, void* d_ws, size_t ws_size,
                              hipStream_t stream) {
  (void)in_sizes; (void)n_in; (void)out_size; (void)ws_size;
  const float* x  = (const float*)d_in[0];
  const float* w1 = (const float*)d_in[1];
  const float* b1 = (const float*)d_in[2];
  const float* a1 = (const float*)d_in[3];
  const float* w2 = (const float*)d_in[4];
  const float* b2 = (const float*)d_in[5];
  const float* a2 = (const float*)d_in[6];
  const float* wa = (const float*)d_in[7];
  const float* ba = (const float*)d_in[8];
  const float* aa = (const float*)d_in[9];
  char* ws = (char*)d_ws;
  float* out = (float*)d_out;

  wcast_kernel<<<dim3(32), dim3(256), 0, stream>>>(w1, w2, wa, ws);
  conv_kernel<<<dim3(512), dim3(256), 0, stream>>>(x, ws, b1, a1, b2, a2, ba, aa);
  attn_kernel<<<dim3(256), dim3(256), 0, stream>>>(ws);
  combine_kernel<<<dim3(1024), dim3(256), 0, stream>>>(ws, out);
}